// Round 1
// baseline (2174.279 us; speedup 1.0000x reference)
//
#include <hip/hip_runtime.h>
#include <hip/hip_bf16.h>
#include <math.h>

// Sizes (fixed by the problem)
#define BB 4
#define MM 4096
#define DD 1024
#define HH 16
#define DH 64
#define RR 64
#define RH 32
#define BM (BB*MM)          // 16384 rows
#define INV_SQRT_RH 0.17677669529663687f

// ---------------------------------------------------------------------------
// Build the rfft matrix C (1024x1024, fx = x @ C) and irfft matrix G
// (1024x1024, y = out2 @ G).
// C[n][j] = cos(2*pi*n*j/1024)/1024            for j in [0,512]
//         = sin(2*pi*n*(j-513)/1024)/1024      for j in [513,1023]
// G[j][n] = (j==0?1:2)*cos(2*pi*n*j/1024)      for j in [0,511]
//         = (t==0?0:2)*sin(2*pi*n*t/1024), t=j-512   for j in [512,1023]
// ---------------------------------------------------------------------------
__global__ __launch_bounds__(256) void build_CG(float* __restrict__ Cm, float* __restrict__ Gm) {
    int idx = blockIdx.x * 256 + threadIdx.x;
    const float w = 6.28318530717958647692f / 1024.0f;
    if (idx < 1048576) {
        int n = idx >> 10, j = idx & 1023;
        float val;
        if (j <= 512) {
            int red = (n * j) & 1023;
            val = cosf(red * w) * (1.0f / 1024.0f);
        } else {
            int t = j - 513;
            int red = (n * t) & 1023;
            val = sinf(red * w) * (1.0f / 1024.0f);
        }
        Cm[idx] = val;
    } else if (idx < 2097152) {
        int l = idx - 1048576;
        int j = l >> 10, n = l & 1023;
        float val;
        if (j < 512) {
            int red = (n * j) & 1023;
            val = (j == 0 ? 1.0f : 2.0f) * cosf(red * w);
        } else {
            int t = j - 512;
            int red = (n * t) & 1023;
            val = (t == 0) ? 0.0f : 2.0f * sinf(red * w);
        }
        Gm[l] = val;
    }
}

__global__ __launch_bounds__(256) void zero_kernel(float* __restrict__ p, int n) {
    int i = blockIdx.x * 256 + threadIdx.x;
    if (i < n) p[i] = 0.0f;
}

// bG[n] = sum_j bp[j] * G[j][n]
__global__ __launch_bounds__(256) void build_bG(const float* __restrict__ bp,
                                                const float* __restrict__ Gm,
                                                float* __restrict__ bG) {
    int n = blockIdx.x * 256 + threadIdx.x;
    if (n < 1024) {
        float s = 0.0f;
        for (int j = 0; j < 1024; ++j) s += bp[j] * Gm[j * 1024 + n];
        bG[n] = s;
    }
}

// bproj[h*32+r] = brf[h][r] + sum_dd b[h*64+dd] * Wrf[h][dd][r]
__global__ __launch_bounds__(256) void build_bproj(const float* __restrict__ b,
                                                   const float* __restrict__ Wrf,
                                                   const float* __restrict__ brf,
                                                   float* __restrict__ bout) {
    int c = blockIdx.x * 256 + threadIdx.x;
    if (c < 512) {
        int h = c >> 5, r = c & 31;
        float s = brf[c];
        for (int dd = 0; dd < 64; ++dd)
            s += b[h * 64 + dd] * Wrf[(size_t)(h * 64 + dd) * 32 + r];
        bout[c] = s;
    }
}

// Wproj[n][h*32+r] = sum_dd Wc[n][h*64+dd] * Wrf[h][dd][r]
__global__ __launch_bounds__(256) void projw(const float* __restrict__ Wc,
                                             const float* __restrict__ Wrf,
                                             float* __restrict__ Wp_) {
    int h = blockIdx.x;            // 0..15
    int n0 = blockIdx.y * 64;      // 16 blocks of 64 rows
    __shared__ float Ws[2048];
    __shared__ float as[8][64];
    int tid = threadIdx.x;
    for (int l = tid; l < 2048; l += 256) Ws[l] = Wrf[(size_t)h * 2048 + l];
    int rr = tid & 31, rowi = tid >> 5;
    for (int s = 0; s < 8; ++s) {
        __syncthreads();
        for (int l = tid; l < 512; l += 256) {
            int rw = l >> 6, cc = l & 63;
            as[rw][cc] = Wc[(size_t)(n0 + s * 8 + rw) * 1024 + h * 64 + cc];
        }
        __syncthreads();
        float p = 0.0f;
        #pragma unroll
        for (int dd = 0; dd < 64; ++dd) p = fmaf(as[rowi][dd], Ws[dd * 32 + rr], p);
        Wp_[(size_t)(n0 + s * 8 + rowi) * 512 + h * 32 + rr] = p;
    }
}

// ---------------------------------------------------------------------------
// Generic 64x64 tiled f32 GEMM, 256 threads, 4x4 per thread.
// op(A): M x K   (TA: A stored K x M)   op(B): K x N  (TB: B stored N x K)
// ---------------------------------------------------------------------------
template<bool TA, bool TB, bool BIAS>
__global__ __launch_bounds__(256) void gemm64(
    const float* __restrict__ A, const float* __restrict__ B,
    const float* __restrict__ bias, float* __restrict__ C,
    int Mdim, int Ndim, int Kdim, int lda, int ldb, int ldc)
{
    __shared__ float As[16][72];
    __shared__ float Bs[16][72];
    const int tid = threadIdx.x;
    const int tx = tid & 15, ty = tid >> 4;
    const int rowBase = blockIdx.y * 64;
    const int colBase = blockIdx.x * 64;
    float acc[4][4] = {};
    for (int k0 = 0; k0 < Kdim; k0 += 16) {
        if (!TA) {
            const int k = tid & 15, i0 = tid >> 4;
            #pragma unroll
            for (int s = 0; s < 4; ++s) {
                int ii = i0 + s * 16;
                As[k][ii] = A[(size_t)(rowBase + ii) * lda + (k0 + k)];
            }
        } else {
            const int i = tid & 63, kq = tid >> 6;
            #pragma unroll
            for (int s = 0; s < 4; ++s) {
                int kk = kq + s * 4;
                As[kk][i] = A[(size_t)(k0 + kk) * lda + (rowBase + i)];
            }
        }
        if (!TB) {
            const int j = tid & 63, kq = tid >> 6;
            #pragma unroll
            for (int s = 0; s < 4; ++s) {
                int kk = kq + s * 4;
                Bs[kk][j] = B[(size_t)(k0 + kk) * ldb + (colBase + j)];
            }
        } else {
            const int k = tid & 15, j0 = tid >> 4;
            #pragma unroll
            for (int s = 0; s < 4; ++s) {
                int jj = j0 + s * 16;
                Bs[k][jj] = B[(size_t)(colBase + jj) * ldb + (k0 + k)];
            }
        }
        __syncthreads();
        #pragma unroll
        for (int k = 0; k < 16; ++k) {
            float a[4], b[4];
            #pragma unroll
            for (int u = 0; u < 4; ++u) a[u] = As[k][ty * 4 + u];
            #pragma unroll
            for (int u = 0; u < 4; ++u) b[u] = Bs[k][tx * 4 + u];
            #pragma unroll
            for (int ii = 0; ii < 4; ++ii)
                #pragma unroll
                for (int jj = 0; jj < 4; ++jj)
                    acc[ii][jj] = fmaf(a[ii], b[jj], acc[ii][jj]);
        }
        __syncthreads();
    }
    #pragma unroll
    for (int ii = 0; ii < 4; ++ii) {
        int row = rowBase + ty * 4 + ii;
        #pragma unroll
        for (int jj = 0; jj < 4; ++jj) {
            int col = colBase + tx * 4 + jj;
            float v = acc[ii][jj];
            if (BIAS) v += bias[col];
            C[(size_t)row * ldc + col] = v;
        }
    }
}

// ---------------------------------------------------------------------------
// KV_sum[bh][r][dd] = sum_m phi_k[bh][m][r] * V[b][m][h*64+dd]
// K_sum[bh][r]      = sum_m phi_k[bh][m][r]
// phi computed on the fly from raw projections Pk. Split-K over m (8 chunks),
// accumulated with f32 atomics into zeroed buffers.
// ---------------------------------------------------------------------------
__global__ __launch_bounds__(256) void kv_reduce(const float* __restrict__ Pk,
                                                 const float* __restrict__ V,
                                                 float* __restrict__ KV,
                                                 float* __restrict__ Ksum) {
    int bx = blockIdx.x;
    int bh = bx >> 3, ch = bx & 7;
    int b = bh >> 4, h = bh & 15;
    __shared__ float ps[4][64], vs[4][64];
    int tid = threadIdx.x;
    int r = tid >> 2, dd0 = (tid & 3) << 4;
    float acc[16] = {};
    float ks = 0.0f;
    int mstart = ch * 512;
    for (int m0 = mstart; m0 < mstart + 512; m0 += 4) {
        __syncthreads();
        if (tid < 128) {
            int rw = tid >> 5, cc = tid & 31;
            float praw = Pk[(size_t)(b * 4096 + m0 + rw) * 512 + h * 32 + cc];
            float sv, cv;
            sincosf(praw, &sv, &cv);
            ps[rw][cc] = cv * INV_SQRT_RH;
            ps[rw][cc + 32] = sv * INV_SQRT_RH;
        } else {
            int l = tid - 128;
            #pragma unroll
            for (int s = 0; s < 2; ++s) {
                int ll = l + s * 128;
                int rw = ll >> 6, cc = ll & 63;
                vs[rw][cc] = V[(size_t)(b * 4096 + m0 + rw) * 1024 + h * 64 + cc];
            }
        }
        __syncthreads();
        #pragma unroll
        for (int mm = 0; mm < 4; ++mm) {
            float p = ps[mm][r];
            if ((tid & 3) == 0) ks += p;
            #pragma unroll
            for (int i = 0; i < 16; ++i) acc[i] = fmaf(p, vs[mm][dd0 + i], acc[i]);
        }
    }
    float* kvb = KV + ((size_t)bh << 12);
    #pragma unroll
    for (int i = 0; i < 16; ++i) atomicAdd(&kvb[(r << 6) + dd0 + i], acc[i]);
    if ((tid & 3) == 0) atomicAdd(&Ksum[(bh << 6) + r], ks);
}

// ---------------------------------------------------------------------------
// attn[b][m][h*64+dd] = (phi_q[m] . KV[:,dd]) / (phi_q[m] . Ksum + 1e-6)
// phi_q computed on the fly from Pq. 32 m-rows per block.
// ---------------------------------------------------------------------------
__global__ __launch_bounds__(256) void attn_out(const float* __restrict__ Pq,
                                                const float* __restrict__ KV,
                                                const float* __restrict__ Ksum,
                                                float* __restrict__ attn) {
    int bh = blockIdx.x;
    int b = bh >> 4, h = bh & 15;
    int m0 = blockIdx.y << 5;
    __shared__ float KVs[64][64];
    __shared__ float Ks[64];
    __shared__ float ps[4][64];
    int tid = threadIdx.x;
    for (int l = tid; l < 4096; l += 256) KVs[l >> 6][l & 63] = KV[((size_t)bh << 12) + l];
    if (tid < 64) Ks[tid] = Ksum[(bh << 6) + tid];
    int rowi = tid >> 6, dd = tid & 63;
    for (int s = 0; s < 8; ++s) {
        __syncthreads();
        if (tid < 128) {
            int rw = tid >> 5, cc = tid & 31;
            float praw = Pq[(size_t)(b * 4096 + m0 + s * 4 + rw) * 512 + h * 32 + cc];
            float sv, cv;
            sincosf(praw, &sv, &cv);
            ps[rw][cc] = cv * INV_SQRT_RH;
            ps[rw][cc + 32] = sv * INV_SQRT_RH;
        }
        __syncthreads();
        float num = 0.0f, den = 1e-6f;
        #pragma unroll
        for (int r = 0; r < 64; ++r) {
            float p = ps[rowi][r];
            num = fmaf(p, KVs[r][dd], num);
            den = fmaf(p, Ks[r], den);
        }
        int m = m0 + (s << 2) + rowi;
        attn[(size_t)(b * 4096 + m) * 1024 + (h << 6) + dd] = num / den;
    }
}

extern "C" void kernel_launch(void* const* d_in, const int* in_sizes, int n_in,
                              void* d_out, int out_size, void* d_ws, size_t ws_size,
                              hipStream_t stream) {
    const float* x   = (const float*)d_in[0];
    const float* Wq  = (const float*)d_in[1];
    const float* bq  = (const float*)d_in[2];
    const float* Wk  = (const float*)d_in[3];
    const float* bk  = (const float*)d_in[4];
    const float* Wv  = (const float*)d_in[5];
    const float* bv  = (const float*)d_in[6];
    const float* Wp  = (const float*)d_in[7];
    const float* bp  = (const float*)d_in[8];
    const float* Wrf = (const float*)d_in[9];
    const float* brf = (const float*)d_in[10];
    float* out = (float*)d_out;
    float* ws  = (float*)d_ws;

    const size_t M1 = 1048576;
    float* C_     = ws;
    float* G_     = ws + M1;
    float* Wtmp   = ws + 2 * M1;
    float* Wcv    = ws + 3 * M1;
    float* WpG    = ws + 4 * M1;
    float* bG     = ws + 5 * M1;          // 1024
    float* bprojQ = ws + 5 * M1 + 2048;   // 512
    float* bprojK = ws + 5 * M1 + 4096;   // 512
    float* WprojQ = ws + 6 * M1;          // 1024x512
    float* WprojK = ws + 7 * M1;
    float* Pq     = ws + 8 * M1;          // 16384x512
    float* Pk     = ws + 16 * M1;         // 16384x512
    float* V      = ws + 24 * M1;         // 16384x1024
    float* attn   = V;                    // alias: V dead after kv_reduce
    float* KV     = ws + 40 * M1;         // 64*64*64
    float* Ksum   = KV + 262144;          // 64*64

    // Build DFT matrices
    build_CG<<<8192, 256, 0, stream>>>(C_, G_);

    // Combined projection weights
    gemm64<false, true, false><<<dim3(16, 16), 256, 0, stream>>>(C_, Wq, nullptr, Wtmp, 1024, 1024, 1024, 1024, 1024, 1024);
    projw<<<dim3(16, 16), 256, 0, stream>>>(Wtmp, Wrf, WprojQ);
    build_bproj<<<2, 256, 0, stream>>>(bq, Wrf, brf, bprojQ);
    gemm64<false, true, false><<<dim3(16, 16), 256, 0, stream>>>(C_, Wk, nullptr, Wtmp, 1024, 1024, 1024, 1024, 1024, 1024);
    projw<<<dim3(16, 16), 256, 0, stream>>>(Wtmp, Wrf, WprojK);
    build_bproj<<<2, 256, 0, stream>>>(bk, Wrf, brf, bprojK);
    gemm64<false, true, false><<<dim3(16, 16), 256, 0, stream>>>(C_, Wv, nullptr, Wcv, 1024, 1024, 1024, 1024, 1024, 1024);
    gemm64<true, false, false><<<dim3(16, 16), 256, 0, stream>>>(Wp, G_, nullptr, WpG, 1024, 1024, 1024, 1024, 1024, 1024);
    build_bG<<<4, 256, 0, stream>>>(bp, G_, bG);

    // Heavy GEMMs: raw RFF projections and V
    gemm64<false, false, true><<<dim3(8, 256), 256, 0, stream>>>(x, WprojQ, bprojQ, Pq, BM, 512, 1024, 1024, 512, 512);
    gemm64<false, false, true><<<dim3(8, 256), 256, 0, stream>>>(x, WprojK, bprojK, Pk, BM, 512, 1024, 1024, 512, 512);
    gemm64<false, false, true><<<dim3(16, 256), 256, 0, stream>>>(x, Wcv, bv, V, BM, 1024, 1024, 1024, 1024, 1024);

    // Linear attention
    zero_kernel<<<(266240 + 255) / 256, 256, 0, stream>>>(KV, 266240);
    kv_reduce<<<512, 256, 0, stream>>>(Pk, V, KV, Ksum);
    attn_out<<<dim3(64, 128), 256, 0, stream>>>(Pq, KV, Ksum, attn);

    // Output projection fused with irfft
    gemm64<false, false, true><<<dim3(16, 256), 256, 0, stream>>>(attn, WpG, bG, out, BM, 1024, 1024, 1024, 1024, 1024);
}

// Round 2
// 1121.463 us; speedup vs baseline: 1.9388x; 1.9388x over previous
//
#include <hip/hip_runtime.h>
#include <hip/hip_bf16.h>
#include <math.h>

// Problem sizes (fixed): B=4, M=4096, D=1024, H=16, d=64, R=64
#define BM 16384
#define INV_SQRT_RH 0.17677669529663687f

typedef _Float16 half8 __attribute__((ext_vector_type(8)));
typedef _Float16 half4v __attribute__((ext_vector_type(4)));
typedef float f32x4 __attribute__((ext_vector_type(4)));

#define GLD16(gp, lp) __builtin_amdgcn_global_load_lds((const __attribute__((address_space(1))) void*)(gp), (__attribute__((address_space(3))) void*)(lp), 16, 0, 0)

// ---------------------------------------------------------------------------
// DFT matrices: fx = x @ C  (rfft+concat+trunc),  y = out2 @ G (irfft)
// ---------------------------------------------------------------------------
__global__ __launch_bounds__(256) void build_CG(float* __restrict__ Cm, float* __restrict__ Gm) {
    int idx = blockIdx.x * 256 + threadIdx.x;
    const float w = 6.28318530717958647692f / 1024.0f;
    if (idx < 1048576) {
        int n = idx >> 10, j = idx & 1023;
        float val;
        if (j <= 512) {
            int red = (n * j) & 1023;
            val = cosf(red * w) * (1.0f / 1024.0f);
        } else {
            int tt = j - 513;
            int red = (n * tt) & 1023;
            val = sinf(red * w) * (1.0f / 1024.0f);
        }
        Cm[idx] = val;
    } else if (idx < 2097152) {
        int l = idx - 1048576;
        int j = l >> 10, n = l & 1023;
        float val;
        if (j < 512) {
            int red = (n * j) & 1023;
            val = (j == 0 ? 1.0f : 2.0f) * cosf(red * w);
        } else {
            int tt = j - 512;
            int red = (n * tt) & 1023;
            val = (tt == 0) ? 0.0f : 2.0f * sinf(red * w);
        }
        Gm[l] = val;
    }
}

__global__ __launch_bounds__(256) void zero_kernel(float* __restrict__ p, int n) {
    int i = blockIdx.x * 256 + threadIdx.x;
    if (i < n) p[i] = 0.0f;
}

// bG[n] = sum_j bp[j]*G[j][n]   -- 64 blocks, 16 n per block, 16 j-slices
__global__ __launch_bounds__(256) void build_bG(const float* __restrict__ bp,
                                                const float* __restrict__ Gm,
                                                float* __restrict__ bG) {
    int b = blockIdx.x, t = threadIdx.x;
    int n = b * 16 + (t & 15), slice = t >> 4;
    float s = 0.0f;
    for (int j = slice * 64; j < slice * 64 + 64; ++j) s += bp[j] * Gm[(size_t)j * 1024 + n];
    __shared__ float red[256];
    red[t] = s;
    __syncthreads();
    if (t < 16) {
        float acc = 0.0f;
        for (int u = 0; u < 16; ++u) acc += red[u * 16 + t];
        bG[b * 16 + t] = acc;
    }
}

// bproj[h*32+r] = brf[h][r] + sum_dd b[h*64+dd]*Wrf[h][dd][r]
__global__ __launch_bounds__(256) void build_bproj(const float* __restrict__ b,
                                                   const float* __restrict__ Wrf,
                                                   const float* __restrict__ brf,
                                                   float* __restrict__ bout) {
    int c = blockIdx.x * 256 + threadIdx.x;
    if (c < 512) {
        int h = c >> 5, r = c & 31;
        float s = brf[c];
        for (int dd = 0; dd < 64; ++dd)
            s += b[h * 64 + dd] * Wrf[(size_t)(h * 64 + dd) * 32 + r];
        bout[c] = s;
    }
}

__global__ __launch_bounds__(256) void copy_vec(const float* __restrict__ src, float* __restrict__ dst, int n) {
    int i = blockIdx.x * 256 + threadIdx.x;
    if (i < n) dst[i] = src[i];
}

// Wproj[n][h*32+r] = sum_dd Wc[n][h*64+dd] * Wrf[h][dd][r]
__global__ __launch_bounds__(256) void projw(const float* __restrict__ Wc,
                                             const float* __restrict__ Wrf,
                                             float* __restrict__ Wp_) {
    int h = blockIdx.x;
    int n0 = blockIdx.y * 64;
    __shared__ float Ws[2048];
    __shared__ float as[8][64];
    int tid = threadIdx.x;
    for (int l = tid; l < 2048; l += 256) Ws[l] = Wrf[(size_t)h * 2048 + l];
    int rr = tid & 31, rowi = tid >> 5;
    for (int s = 0; s < 8; ++s) {
        __syncthreads();
        for (int l = tid; l < 512; l += 256) {
            int rw = l >> 6, cc = l & 63;
            as[rw][cc] = Wc[(size_t)(n0 + s * 8 + rw) * 1024 + h * 64 + cc];
        }
        __syncthreads();
        float p = 0.0f;
        #pragma unroll
        for (int dd = 0; dd < 64; ++dd) p = fmaf(as[rowi][dd], Ws[dd * 32 + rr], p);
        Wp_[(size_t)(n0 + s * 8 + rowi) * 512 + h * 32 + rr] = p;
    }
}

// ---------------------------------------------------------------------------
// Generic f32 64x64-tile GEMM body (preprocessing only)
// ---------------------------------------------------------------------------
template<bool TA, bool TB>
__device__ __forceinline__ void gemm64_body(
    const float* __restrict__ A, const float* __restrict__ B,
    float* __restrict__ C, int Kdim, int lda, int ldb, int ldc,
    int rowBase, int colBase)
{
    __shared__ float As[16][72];
    __shared__ float Bs[16][72];
    const int tid = threadIdx.x;
    const int tx = tid & 15, ty = tid >> 4;
    float acc[4][4] = {};
    for (int k0 = 0; k0 < Kdim; k0 += 16) {
        if (!TA) {
            const int k = tid & 15, i0 = tid >> 4;
            #pragma unroll
            for (int s = 0; s < 4; ++s) {
                int ii = i0 + s * 16;
                As[k][ii] = A[(size_t)(rowBase + ii) * lda + (k0 + k)];
            }
        } else {
            const int i = tid & 63, kq = tid >> 6;
            #pragma unroll
            for (int s = 0; s < 4; ++s) {
                int kk = kq + s * 4;
                As[kk][i] = A[(size_t)(k0 + kk) * lda + (rowBase + i)];
            }
        }
        if (!TB) {
            const int j = tid & 63, kq = tid >> 6;
            #pragma unroll
            for (int s = 0; s < 4; ++s) {
                int kk = kq + s * 4;
                Bs[kk][j] = B[(size_t)(k0 + kk) * ldb + (colBase + j)];
            }
        } else {
            const int k = tid & 15, j0 = tid >> 4;
            #pragma unroll
            for (int s = 0; s < 4; ++s) {
                int jj = j0 + s * 16;
                Bs[k][jj] = B[(size_t)(colBase + jj) * ldb + (k0 + k)];
            }
        }
        __syncthreads();
        #pragma unroll
        for (int k = 0; k < 16; ++k) {
            float a[4], b[4];
            #pragma unroll
            for (int u = 0; u < 4; ++u) a[u] = As[k][ty * 4 + u];
            #pragma unroll
            for (int u = 0; u < 4; ++u) b[u] = Bs[k][tx * 4 + u];
            #pragma unroll
            for (int ii = 0; ii < 4; ++ii)
                #pragma unroll
                for (int jj = 0; jj < 4; ++jj)
                    acc[ii][jj] = fmaf(a[ii], b[jj], acc[ii][jj]);
        }
        __syncthreads();
    }
    #pragma unroll
    for (int ii = 0; ii < 4; ++ii) {
        int row = rowBase + ty * 4 + ii;
        #pragma unroll
        for (int jj = 0; jj < 4; ++jj)
            C[(size_t)row * ldc + colBase + tx * 4 + jj] = acc[ii][jj];
    }
}

// z-batched: Wt_z = Cm @ W_z^T  for z in {q,k,v}, all 1024^3
__global__ __launch_bounds__(256) void gemm_pre3(
    const float* __restrict__ Cm,
    const float* __restrict__ B0, const float* __restrict__ B1, const float* __restrict__ B2,
    float* __restrict__ C0, float* __restrict__ C1, float* __restrict__ C2)
{
    int z = blockIdx.z;
    const float* B = (z == 0) ? B0 : (z == 1) ? B1 : B2;
    float* C = (z == 0) ? C0 : (z == 1) ? C1 : C2;
    gemm64_body<false, true>(Cm, B, C, 1024, 1024, 1024, 1024, blockIdx.y * 64, blockIdx.x * 64);
}

// WpGT[n][j] = sum_o G[o][n]*Wp[o][j]   (i.e. (Wp^T @ G)^T, directly transposed)
__global__ __launch_bounds__(256) void gemm_wpgt(
    const float* __restrict__ G, const float* __restrict__ Wp, float* __restrict__ C)
{
    gemm64_body<true, false>(G, Wp, C, 1024, 1024, 1024, 1024, blockIdx.y * 64, blockIdx.x * 64);
}

// ---------------------------------------------------------------------------
// fp16 hi/lo split conversions.  lo is pre-scaled by 2048 so it stays in
// fp16 normal range (unscaled lo of small-sigma weights would hit subnormal
// quantization at 2^-25 abs -> 4e-5 rel error -> fails threshold via den).
// ---------------------------------------------------------------------------
__global__ __launch_bounds__(256) void split_plain(const float* __restrict__ src,
        _Float16* __restrict__ hi, _Float16* __restrict__ lo, int n4) {
    int stride = gridDim.x * 256;
    for (int i = blockIdx.x * 256 + threadIdx.x; i < n4; i += stride) {
        float4 v = ((const float4*)src)[i];
        _Float16 h0 = (_Float16)v.x, h1 = (_Float16)v.y, h2 = (_Float16)v.z, h3 = (_Float16)v.w;
        ((half4v*)hi)[i] = (half4v){h0, h1, h2, h3};
        ((half4v*)lo)[i] = (half4v){(_Float16)((v.x - (float)h0) * 2048.0f),
                                    (_Float16)((v.y - (float)h1) * 2048.0f),
                                    (_Float16)((v.z - (float)h2) * 2048.0f),
                                    (_Float16)((v.w - (float)h3) * 2048.0f)};
    }
}

// transpose + split: src f32 [1024][N] -> hi/lo fp16 [N][1024]
__global__ __launch_bounds__(256) void split_T(const float* __restrict__ src, int N,
        _Float16* __restrict__ hi, _Float16* __restrict__ lo) {
    __shared__ float tile[32][33];
    int n0 = blockIdx.x * 32, k0 = blockIdx.y * 32;
    int t = threadIdx.x, tx = t & 31, ty = t >> 5;
    #pragma unroll
    for (int s = 0; s < 4; ++s)
        tile[ty + s * 8][tx] = src[(size_t)(k0 + ty + s * 8) * N + n0 + tx];
    __syncthreads();
    #pragma unroll
    for (int s = 0; s < 4; ++s) {
        int n = n0 + ty + s * 8;
        float v = tile[tx][ty + s * 8];
        _Float16 h = (_Float16)v;
        size_t o = (size_t)n * 1024 + k0 + tx;
        hi[o] = h;
        lo[o] = (_Float16)((v - (float)h) * 2048.0f);
    }
}

// ---------------------------------------------------------------------------
// MFMA GEMM, fp16 two-term split:  C = Ah*Bh + (Ah*Bl + Al*Bh)/2048 + bias
// A: [M][K] hi/lo fp16, B: [N][K] hi/lo fp16 (transposed weights), C: f32 [M][N]
// Tile 128(M) x 64(N), 4 waves (2x2), BK=32, global_load_lds w/ swizzled src.
// ---------------------------------------------------------------------------
__global__ __launch_bounds__(256) void gemm_hilo(
    const _Float16* __restrict__ Ah, const _Float16* __restrict__ Al,
    const _Float16* __restrict__ Bh, const _Float16* __restrict__ Bl,
    const float* __restrict__ bias, float* __restrict__ Cout,
    int Ndim, int Kdim)
{
    __shared__ _Float16 lds[12288];  // Ah[0,4K) Al[4K,8K) Bh[8K,10K) Bl[10K,12K) (halves)
    const int t = threadIdx.x;
    const int rowBase = blockIdx.y * 128;
    const int colBase = blockIdx.x * 64;

    // staging: thread t owns LDS slot (row=t>>2, cb=t&3); source col-block is
    // XOR-swizzled so ds_read_b128 frag reads are bank-conflict-free
    const int srow = t >> 2;
    const int scb = (t & 3) ^ ((t >> 4) & 3);
    const size_t aoff = (size_t)(rowBase + srow) * Kdim + scb * 8;
    const size_t boff = (size_t)(colBase + srow) * Kdim + scb * 8;
    const _Float16* pa0 = Ah + aoff;
    const _Float16* pa1 = Ah + aoff + (size_t)64 * Kdim;
    const _Float16* qa0 = Al + aoff;
    const _Float16* qa1 = Al + aoff + (size_t)64 * Kdim;
    const _Float16* pb = Bh + boff;
    const _Float16* qb = Bl + boff;
    _Float16* l_a0 = lds + t * 8;
    _Float16* l_a1 = lds + t * 8 + 2048;
    _Float16* l_la0 = lds + 4096 + t * 8;
    _Float16* l_la1 = lds + 4096 + t * 8 + 2048;
    _Float16* l_b = lds + 8192 + t * 8;
    _Float16* l_lb = lds + 10240 + t * 8;

    const int l = t & 63;
    const int w = t >> 6;
    const int wr = w >> 1, wc = w & 1;
    const int frow = l & 15;
    const int fcb = ((l >> 4) ^ ((l >> 2) & 3)) & 3;
    int aidx[4], bidx[2];
    #pragma unroll
    for (int i = 0; i < 4; ++i) aidx[i] = (wr * 64 + i * 16 + frow) * 32 + fcb * 8;
    #pragma unroll
    for (int j = 0; j < 2; ++j) bidx[j] = (wc * 32 + j * 16 + frow) * 32 + fcb * 8;

    f32x4 acc_h[4][2], acc_c[4][2];
    #pragma unroll
    for (int i = 0; i < 4; ++i)
        #pragma unroll
        for (int j = 0; j < 2; ++j) {
            acc_h[i][j] = (f32x4){0.0f, 0.0f, 0.0f, 0.0f};
            acc_c[i][j] = (f32x4){0.0f, 0.0f, 0.0f, 0.0f};
        }

    for (int k0 = 0; k0 < Kdim; k0 += 32) {
        __syncthreads();
        GLD16(pa0 + k0, l_a0);
        GLD16(pa1 + k0, l_a1);
        GLD16(qa0 + k0, l_la0);
        GLD16(qa1 + k0, l_la1);
        GLD16(pb + k0, l_b);
        GLD16(qb + k0, l_lb);
        __syncthreads();
        half8 a_h[4], a_l[4], b_h[2], b_l[2];
        #pragma unroll
        for (int i = 0; i < 4; ++i) {
            a_h[i] = *(const half8*)&lds[aidx[i]];
            a_l[i] = *(const half8*)&lds[4096 + aidx[i]];
        }
        #pragma unroll
        for (int j = 0; j < 2; ++j) {
            b_h[j] = *(const half8*)&lds[8192 + bidx[j]];
            b_l[j] = *(const half8*)&lds[10240 + bidx[j]];
        }
        #pragma unroll
        for (int i = 0; i < 4; ++i)
            #pragma unroll
            for (int j = 0; j < 2; ++j) {
                acc_h[i][j] = __builtin_amdgcn_mfma_f32_16x16x32_f16(a_h[i], b_h[j], acc_h[i][j], 0, 0, 0);
                acc_c[i][j] = __builtin_amdgcn_mfma_f32_16x16x32_f16(a_h[i], b_l[j], acc_c[i][j], 0, 0, 0);
                acc_c[i][j] = __builtin_amdgcn_mfma_f32_16x16x32_f16(a_l[i], b_h[j], acc_c[i][j], 0, 0, 0);
            }
    }

    #pragma unroll
    for (int i = 0; i < 4; ++i) {
        const int rg0 = rowBase + wr * 64 + i * 16 + (l >> 4) * 4;
        #pragma unroll
        for (int j = 0; j < 2; ++j) {
            const int cg = colBase + wc * 32 + j * 16 + frow;
            const float bb = bias[cg];
            #pragma unroll
            for (int r = 0; r < 4; ++r)
                Cout[(size_t)(rg0 + r) * Ndim + cg] = acc_h[i][j][r] + acc_c[i][j][r] * (1.0f / 2048.0f) + bb;
        }
    }
}

// ---------------------------------------------------------------------------
// KV[bh][r][dd] = sum_m phi_k[m][r]*V[m][dd];  Ksum[bh][r] = sum_m phi_k[m][r]
// P/V read from fused PQV buffer [16384][2048] (Pq | Pk | V)
// ---------------------------------------------------------------------------
__global__ __launch_bounds__(256) void kv_reduce(const float* __restrict__ PQV,
                                                 float* __restrict__ KV,
                                                 float* __restrict__ Ksum) {
    int bx = blockIdx.x;
    int bh = bx >> 3, ch = bx & 7;
    int b = bh >> 4, h = bh & 15;
    __shared__ float ps[4][64], vs[4][64];
    int tid = threadIdx.x;
    int r = tid >> 2, dd0 = (tid & 3) << 4;
    float acc[16] = {};
    float ks = 0.0f;
    int mstart = ch * 512;
    for (int m0 = mstart; m0 < mstart + 512; m0 += 4) {
        __syncthreads();
        if (tid < 128) {
            int rw = tid >> 5, cc = tid & 31;
            float praw = PQV[(size_t)(b * 4096 + m0 + rw) * 2048 + 512 + h * 32 + cc];
            float sv, cv;
            sincosf(praw, &sv, &cv);
            ps[rw][cc] = cv * INV_SQRT_RH;
            ps[rw][cc + 32] = sv * INV_SQRT_RH;
        } else {
            int ll = tid - 128;
            #pragma unroll
            for (int s = 0; s < 2; ++s) {
                int l2 = ll + s * 128;
                int rw = l2 >> 6, cc = l2 & 63;
                vs[rw][cc] = PQV[(size_t)(b * 4096 + m0 + rw) * 2048 + 1024 + h * 64 + cc];
            }
        }
        __syncthreads();
        #pragma unroll
        for (int mm = 0; mm < 4; ++mm) {
            float p = ps[mm][r];
            if ((tid & 3) == 0) ks += p;
            #pragma unroll
            for (int i = 0; i < 16; ++i) acc[i] = fmaf(p, vs[mm][dd0 + i], acc[i]);
        }
    }
    float* kvb = KV + ((size_t)bh << 12);
    #pragma unroll
    for (int i = 0; i < 16; ++i) atomicAdd(&kvb[(r << 6) + dd0 + i], acc[i]);
    if ((tid & 3) == 0) atomicAdd(&Ksum[(bh << 6) + r], ks);
}

// attn (written directly as fp16 hi/lo for the final MFMA GEMM)
__global__ __launch_bounds__(256) void attn_out(const float* __restrict__ PQV,
                                                const float* __restrict__ KV,
                                                const float* __restrict__ Ksum,
                                                _Float16* __restrict__ ah,
                                                _Float16* __restrict__ al) {
    int bh = blockIdx.x;
    int b = bh >> 4, h = bh & 15;
    int m0 = blockIdx.y << 5;
    __shared__ float KVs[64][64];
    __shared__ float Ks[64];
    __shared__ float ps[4][64];
    int tid = threadIdx.x;
    for (int l = tid; l < 4096; l += 256) KVs[l >> 6][l & 63] = KV[((size_t)bh << 12) + l];
    if (tid < 64) Ks[tid] = Ksum[(bh << 6) + tid];
    int rowi = tid >> 6, dd = tid & 63;
    for (int s = 0; s < 8; ++s) {
        __syncthreads();
        if (tid < 128) {
            int rw = tid >> 5, cc = tid & 31;
            float praw = PQV[(size_t)(b * 4096 + m0 + s * 4 + rw) * 2048 + h * 32 + cc];
            float sv, cv;
            sincosf(praw, &sv, &cv);
            ps[rw][cc] = cv * INV_SQRT_RH;
            ps[rw][cc + 32] = sv * INV_SQRT_RH;
        }
        __syncthreads();
        float num = 0.0f, den = 1e-6f;
        #pragma unroll
        for (int r = 0; r < 64; ++r) {
            float p = ps[rowi][r];
            num = fmaf(p, KVs[r][dd], num);
            den = fmaf(p, Ks[r], den);
        }
        int m = m0 + (s << 2) + rowi;
        float v = num / den;
        _Float16 hh = (_Float16)v;
        size_t o = (size_t)(b * 4096 + m) * 1024 + (h << 6) + dd;
        ah[o] = hh;
        al[o] = (_Float16)((v - (float)hh) * 2048.0f);
    }
}

extern "C" void kernel_launch(void* const* d_in, const int* in_sizes, int n_in,
                              void* d_out, int out_size, void* d_ws, size_t ws_size,
                              hipStream_t stream) {
    const float* x   = (const float*)d_in[0];
    const float* Wq  = (const float*)d_in[1];
    const float* bq  = (const float*)d_in[2];
    const float* Wk  = (const float*)d_in[3];
    const float* bk  = (const float*)d_in[4];
    const float* Wv  = (const float*)d_in[5];
    const float* bv  = (const float*)d_in[6];
    const float* Wp  = (const float*)d_in[7];
    const float* bp  = (const float*)d_in[8];
    const float* Wrf = (const float*)d_in[9];
    const float* brf = (const float*)d_in[10];
    float* out = (float*)d_out;
    float* ws  = (float*)d_ws;

    const size_t M1 = 1048576;
    float* C_      = ws;                       // 1M
    float* G_      = ws + 1 * M1;              // 1M
    float* Wtq     = ws + 2 * M1;              // 1M
    float* Wtk     = ws + 3 * M1;              // 1M
    float* Wcv_    = ws + 4 * M1;              // 1M
    float* WpGT_   = ws + 5 * M1;              // 1M (already [N][K])
    float* WprojQ  = ws + 6 * M1;              // 0.5M  [1024][512]
    float* WprojK  = ws + 6 * M1 + 524288;     // 0.5M
    float* bias_cat= ws + 7 * M1;              // 2048
    float* bG      = ws + 7 * M1 + 2048;       // 1024
    float* KV      = ws + 7 * M1 + 8192;       // 262144
    float* Ksum    = KV + 262144;              // 4096
    float* PQV     = ws + 8 * M1;              // 32M f32: [16384][2048] = Pq|Pk|V

    _Float16* wsH   = (_Float16*)(ws + 40 * M1);
    _Float16* xh    = wsH;                      // 16.7M halves (reused as attn hi)
    _Float16* xl    = wsH + 16777216;           // (reused as attn lo)
    _Float16* WcatH = wsH + 33554432;           // [2048][1024]: WprojQT|WprojKT|WcvT
    _Float16* WcatL = wsH + 35651584;
    _Float16* WpGTh = wsH + 37748736;           // [1024][1024]
    _Float16* WpGTl = wsH + 38797312;

    // --- build DFT matrices + input split ---
    build_CG<<<8192, 256, 0, stream>>>(C_, G_);
    split_plain<<<4096, 256, 0, stream>>>(x, xh, xl, 4194304);

    // --- preprocessing (weight-space, small) ---
    gemm_pre3<<<dim3(16, 16, 3), 256, 0, stream>>>(C_, Wq, Wk, Wv, Wtq, Wtk, Wcv_);
    gemm_wpgt<<<dim3(16, 16), 256, 0, stream>>>(G_, Wp, WpGT_);
    projw<<<dim3(16, 16), 256, 0, stream>>>(Wtq, Wrf, WprojQ);
    projw<<<dim3(16, 16), 256, 0, stream>>>(Wtk, Wrf, WprojK);
    build_bproj<<<2, 256, 0, stream>>>(bq, Wrf, brf, bias_cat);
    build_bproj<<<2, 256, 0, stream>>>(bk, Wrf, brf, bias_cat + 512);
    copy_vec<<<4, 256, 0, stream>>>(bv, bias_cat + 1024, 1024);
    build_bG<<<64, 256, 0, stream>>>(bp, G_, bG);
    split_T<<<dim3(16, 32), 256, 0, stream>>>(WprojQ, 512, WcatH, WcatL);
    split_T<<<dim3(16, 32), 256, 0, stream>>>(WprojK, 512, WcatH + 524288, WcatL + 524288);
    split_T<<<dim3(32, 32), 256, 0, stream>>>(Wcv_, 1024, WcatH + 1048576, WcatL + 1048576);
    split_plain<<<1024, 256, 0, stream>>>(WpGT_, WpGTh, WpGTl, 262144);

    // --- heavy GEMM 1: PQV = x @ [WprojQ | WprojK | Wcv] + bias ---
    gemm_hilo<<<dim3(32, 128), 256, 0, stream>>>(xh, xl, WcatH, WcatL, bias_cat, PQV, 2048, 1024);

    // --- linear attention ---
    zero_kernel<<<(266240 + 255) / 256, 256, 0, stream>>>(KV, 266240);
    kv_reduce<<<512, 256, 0, stream>>>(PQV, KV, Ksum);
    attn_out<<<dim3(64, 128), 256, 0, stream>>>(PQV, KV, Ksum, xh, xl);  // attn aliases x

    // --- heavy GEMM 2: out = attn @ WpG + bG (irfft folded in) ---
    gemm_hilo<<<dim3(16, 128), 256, 0, stream>>>(xh, xl, WpGTh, WpGTl, bG, out, 1024, 1024);
}